// Round 10
// baseline (1513.685 us; speedup 1.0000x reference)
//
#include <hip/hip_runtime.h>
#include <hip/hip_bf16.h>

// Problem constants
#define BB 64
#define TT 2048
#define II 128
#define HH 256
#define OO 128

typedef float f32x4v __attribute__((ext_vector_type(4)));
typedef short bf16x8 __attribute__((ext_vector_type(8)));
typedef unsigned short ushortv4 __attribute__((ext_vector_type(4)));

__device__ __forceinline__ float bf16bits_to_f32(unsigned short u) {
    return __uint_as_float((unsigned)u << 16);
}
__device__ __forceinline__ unsigned short f2bf(float f) {
    union { __hip_bfloat16 h; unsigned short u; } cv;
    cv.h = __float2bfloat16(f);   // RNE
    return cv.u;
}
__device__ __forceinline__ float tanh_fast(float x) {
    // tanh(x) = 1 - 2/(e^{2x}+1);  e^{2x} = 2^{x*2*log2(e)}
    float y = x * 2.88539008177793f;
    float e;
    asm("v_exp_f32 %0, %1" : "=v"(e) : "v"(y));
    return fmaf(-2.0f, __builtin_amdgcn_rcpf(e + 1.0f), 1.0f);
}

// within-32 permutation: storage position p holds true column
//   T(p) = (p & ~31) + 16*(p&1) + ((p&31)>>1)
// inverse: pos(c) = (c & ~31) + 2*(c&15) + ((c&31)>>4)

// ---------------------------------------------------------------------------
// Phase 1 GEMM: xproj[m][pos] = (x*Wi^T)[m][T(pos)] + bi + bh  (unchanged R8)
// ---------------------------------------------------------------------------
#define BM 64
#define BN 64
#define BKT 32

__global__ __launch_bounds__(256) void gemm_f32_bt(
    const float* __restrict__ A, const float* __restrict__ B,
    const float* __restrict__ bias, const float* __restrict__ bias2,
    float* __restrict__ C, int M, int N, int K)
{
    __shared__ __align__(16) float As[BKT][BM + 4];
    __shared__ __align__(16) float Bs[BKT][BN + 4];

    const int t  = threadIdx.x;
    const int m0 = blockIdx.x * BM;
    const int n0 = blockIdx.y * BN;
    const int r  = t >> 3;         // 0..31
    const int kq = (t & 7) * 4;    // 0,4,...,28
    const int tx = t & 15;
    const int ty = t >> 4;

    float acc[4][4] = {};

    for (int k0 = 0; k0 < K; k0 += BKT) {
        float4 a0 = *(const float4*)&A[(size_t)(m0 + r)      * K + k0 + kq];
        float4 a1 = *(const float4*)&A[(size_t)(m0 + r + 32) * K + k0 + kq];
        float4 b0 = *(const float4*)&B[(size_t)(n0 + r)      * K + k0 + kq];
        float4 b1 = *(const float4*)&B[(size_t)(n0 + r + 32) * K + k0 + kq];

        __syncthreads();
        As[kq + 0][r] = a0.x; As[kq + 1][r] = a0.y; As[kq + 2][r] = a0.z; As[kq + 3][r] = a0.w;
        As[kq + 0][r + 32] = a1.x; As[kq + 1][r + 32] = a1.y; As[kq + 2][r + 32] = a1.z; As[kq + 3][r + 32] = a1.w;
        Bs[kq + 0][r] = b0.x; Bs[kq + 1][r] = b0.y; Bs[kq + 2][r] = b0.z; Bs[kq + 3][r] = b0.w;
        Bs[kq + 0][r + 32] = b1.x; Bs[kq + 1][r + 32] = b1.y; Bs[kq + 2][r + 32] = b1.z; Bs[kq + 3][r + 32] = b1.w;
        __syncthreads();

#pragma unroll
        for (int k = 0; k < BKT; ++k) {
            float4 avv = *(const float4*)&As[k][ty * 4];
            float4 bvv = *(const float4*)&Bs[k][tx * 4];
            const float* av = &avv.x;
            const float* bv = &bvv.x;
#pragma unroll
            for (int i = 0; i < 4; ++i)
#pragma unroll
                for (int j = 0; j < 4; ++j)
                    acc[i][j] = fmaf(av[i], bv[j], acc[i][j]);
        }
    }

#pragma unroll
    for (int i = 0; i < 4; ++i) {
#pragma unroll
        for (int j = 0; j < 4; ++j) {
            const int c = n0 + tx * 4 + j;     // true column
            float v = acc[i][j] + bias[c] + bias2[c];
            const int pos = (c & ~31) + 2 * (c & 15) + ((c & 31) >> 4);
            C[(size_t)(m0 + ty * 4 + i) * N + pos] = v;
        }
    }
}

// ---------------------------------------------------------------------------
// Phase 3 GEMM (unchanged R8): hs bf16 within-32 permuted; As staging
// un-permutes (rows {kh, kh+16, kh+1, kh+17}).
// ---------------------------------------------------------------------------
__global__ __launch_bounds__(256) void gemm_bf16a_bt(
    const unsigned short* __restrict__ A, const float* __restrict__ B,
    const float* __restrict__ bias, float* __restrict__ C,
    int M, int N, int K)
{
    __shared__ __align__(16) float As[BKT][BM + 4];
    __shared__ __align__(16) float Bs[BKT][BN + 4];

    const int t  = threadIdx.x;
    const int m0 = blockIdx.x * BM;
    const int n0 = blockIdx.y * BN;
    const int r  = t >> 3;
    const int kq = (t & 7) * 4;
    const int kh = kq >> 1;        // un-permute
    const int tx = t & 15;
    const int ty = t >> 4;

    float acc[4][4] = {};

    for (int k0 = 0; k0 < K; k0 += BKT) {
        ushortv4 a0 = *(const ushortv4*)&A[(size_t)(m0 + r)      * K + k0 + kq];
        ushortv4 a1 = *(const ushortv4*)&A[(size_t)(m0 + r + 32) * K + k0 + kq];
        float4  b0 = *(const float4*)&B[(size_t)(n0 + r)      * K + k0 + kq];
        float4  b1 = *(const float4*)&B[(size_t)(n0 + r + 32) * K + k0 + kq];

        __syncthreads();
        As[kh + 0][r]  = bf16bits_to_f32(a0[0]); As[kh + 16][r] = bf16bits_to_f32(a0[1]);
        As[kh + 1][r]  = bf16bits_to_f32(a0[2]); As[kh + 17][r] = bf16bits_to_f32(a0[3]);
        As[kh + 0][r + 32]  = bf16bits_to_f32(a1[0]); As[kh + 16][r + 32] = bf16bits_to_f32(a1[1]);
        As[kh + 1][r + 32]  = bf16bits_to_f32(a1[2]); As[kh + 17][r + 32] = bf16bits_to_f32(a1[3]);
        Bs[kq + 0][r] = b0.x; Bs[kq + 1][r] = b0.y; Bs[kq + 2][r] = b0.z; Bs[kq + 3][r] = b0.w;
        Bs[kq + 0][r + 32] = b1.x; Bs[kq + 1][r + 32] = b1.y; Bs[kq + 2][r + 32] = b1.z; Bs[kq + 3][r + 32] = b1.w;
        __syncthreads();

#pragma unroll
        for (int k = 0; k < BKT; ++k) {
            float4 avv = *(const float4*)&As[k][ty * 4];
            float4 bvv = *(const float4*)&Bs[k][tx * 4];
            const float* av = &avv.x;
            const float* bv = &bvv.x;
#pragma unroll
            for (int i = 0; i < 4; ++i)
#pragma unroll
                for (int j = 0; j < 4; ++j)
                    acc[i][j] = fmaf(av[i], bv[j], acc[i][j]);
        }
    }

#pragma unroll
    for (int i = 0; i < 4; ++i) {
        float4 o;
        o.x = acc[i][0] + bias[n0 + tx * 4 + 0];
        o.y = acc[i][1] + bias[n0 + tx * 4 + 1];
        o.z = acc[i][2] + bias[n0 + tx * 4 + 2];
        o.w = acc[i][3] + bias[n0 + tx * 4 + 3];
        *(float4*)&C[(size_t)(m0 + ty * 4 + i) * N + n0 + tx * 4] = o;
    }
}

// ---------------------------------------------------------------------------
// Recurrence v9 = v8 +:
//  (a) x loads for t+1 issued right after the ds_reads (BEFORE MFMAs)
//  (b) raw barrier: lgkmcnt(0)-only (no vmcnt drain)
//  (c) unroll-2, compile-time parity, ping-pong registers, offset immediates
// ---------------------------------------------------------------------------
#define G 16
#define HPAD 264    // ushorts per h row (528B)

__global__ __launch_bounds__(512) __attribute__((amdgpu_waves_per_eu(2, 2)))
void rnn_recurrence_mfma(
    const float* __restrict__ xproj, const float* __restrict__ Wh,
    unsigned short* __restrict__ hs)
{
    __shared__ __align__(16) unsigned short hbl[2][G][HPAD];

    const int blk  = blockIdx.x;         // 0..3
    const int tid  = threadIdx.x;        // 0..511
    const int wave = tid >> 6;           // 0..7
    const int lane = tid & 63;
    const int l15  = lane & 15;
    const int lg   = lane >> 4;          // 0..3
    const int n0   = wave * 32;          // wave's 32-unit block

    // ---- one-time B-frags (within-32 K-gather, v6/v8-verified)
#define LOADB(nt, kt, dst) { \
        const float* wp = Wh + (size_t)(n0 + (nt)*16 + l15) * HH + (kt)*32 + lg*4; \
        dst[0] = (short)f2bf(wp[0]);  dst[1] = (short)f2bf(wp[16]); \
        dst[2] = (short)f2bf(wp[1]);  dst[3] = (short)f2bf(wp[17]); \
        dst[4] = (short)f2bf(wp[2]);  dst[5] = (short)f2bf(wp[18]); \
        dst[6] = (short)f2bf(wp[3]);  dst[7] = (short)f2bf(wp[19]); }

    bf16x8 B00, B01, B02, B03, B04, B05, B06, B07;
    bf16x8 B10, B11, B12, B13, B14, B15, B16, B17;
    LOADB(0, 0, B00) LOADB(0, 1, B01) LOADB(0, 2, B02) LOADB(0, 3, B03)
    LOADB(0, 4, B04) LOADB(0, 5, B05) LOADB(0, 6, B06) LOADB(0, 7, B07)
    LOADB(1, 0, B10) LOADB(1, 1, B11) LOADB(1, 2, B12) LOADB(1, 3, B13)
    LOADB(1, 4, B14) LOADB(1, 5, B15) LOADB(1, 6, B16) LOADB(1, 7, B17)

    // per-thread 4 batch rows (m = lg*4 + r), permuted col offset n0 + 2*l15
    const int mb = blk * G + lg * 4;
    const float* xq0 = xproj + (size_t)(mb + 0) * TT * HH + n0 + 2 * l15;
    const float* xq1 = xproj + (size_t)(mb + 1) * TT * HH + n0 + 2 * l15;
    const float* xq2 = xproj + (size_t)(mb + 2) * TT * HH + n0 + 2 * l15;
    const float* xq3 = xproj + (size_t)(mb + 3) * TT * HH + n0 + 2 * l15;
    // store bases start at position t = -1 (never stored; COND guards t=0)
    unsigned short* hq0 = hs + (size_t)(mb + 0) * TT * HH + n0 + 2 * l15 - HH;
    unsigned short* hq1 = hs + (size_t)(mb + 1) * TT * HH + n0 + 2 * l15 - HH;
    unsigned short* hq2 = hs + (size_t)(mb + 2) * TT * HH + n0 + 2 * l15 - HH;
    unsigned short* hq3 = hs + (size_t)(mb + 3) * TT * HH + n0 + 2 * l15 - HH;

    // prologue: zero h buffer 0; load x for t=0
    for (int i = tid; i < G * HPAD / 2; i += 512)
        ((unsigned int*)hbl[0])[i] = 0u;
    float2 xvA0 = *(const float2*)xq0;
    float2 xvA1 = *(const float2*)xq1;
    float2 xvA2 = *(const float2*)xq2;
    float2 xvA3 = *(const float2*)xq3;
    float2 xvB0, xvB1, xvB2, xvB3;
    unsigned int svA0 = 0, svA1 = 0, svA2 = 0, svA3 = 0;
    unsigned int svB0 = 0, svB1 = 0, svB2 = 0, svB3 = 0;
    __syncthreads();

    // one step: parity P (compile-time), XC = current x regs, XN = next x regs
    // (loaded early), SVST = packed h of step-1 (stored), SVNEW = this step's.
#define MM(a, b, c) c = __builtin_amdgcn_mfma_f32_16x16x32_bf16(a, b, c, 0, 0, 0);
#define STEP(P, XC, XN, SVST, SVNEW, COND, LOFF, SOFF) { \
    const unsigned short* hrow = &hbl[P][l15][lg * 8]; \
    bf16x8 a0 = *(const bf16x8*)(hrow + 0 * 32); \
    bf16x8 a1 = *(const bf16x8*)(hrow + 1 * 32); \
    bf16x8 a2 = *(const bf16x8*)(hrow + 2 * 32); \
    bf16x8 a3 = *(const bf16x8*)(hrow + 3 * 32); \
    bf16x8 a4 = *(const bf16x8*)(hrow + 4 * 32); \
    bf16x8 a5 = *(const bf16x8*)(hrow + 5 * 32); \
    bf16x8 a6 = *(const bf16x8*)(hrow + 6 * 32); \
    bf16x8 a7 = *(const bf16x8*)(hrow + 7 * 32); \
    XN##0 = *(const float2*)((const char*)xq0 + (LOFF)); \
    XN##1 = *(const float2*)((const char*)xq1 + (LOFF)); \
    XN##2 = *(const float2*)((const char*)xq2 + (LOFF)); \
    XN##3 = *(const float2*)((const char*)xq3 + (LOFF)); \
    if (COND) { \
        *(unsigned int*)((char*)hq0 + (SOFF)) = SVST##0; \
        *(unsigned int*)((char*)hq1 + (SOFF)) = SVST##1; \
        *(unsigned int*)((char*)hq2 + (SOFF)) = SVST##2; \
        *(unsigned int*)((char*)hq3 + (SOFF)) = SVST##3; \
    } \
    f32x4v c0 = {(XC##0).x, (XC##1).x, (XC##2).x, (XC##3).x}; \
    f32x4v c1 = {(XC##0).y, (XC##1).y, (XC##2).y, (XC##3).y}; \
    MM(a0, B00, c0) MM(a0, B10, c1) \
    MM(a1, B01, c0) MM(a1, B11, c1) \
    MM(a2, B02, c0) MM(a2, B12, c1) \
    MM(a3, B03, c0) MM(a3, B13, c1) \
    MM(a4, B04, c0) MM(a4, B14, c1) \
    MM(a5, B05, c0) MM(a5, B15, c1) \
    MM(a6, B06, c0) MM(a6, B16, c1) \
    MM(a7, B07, c0) MM(a7, B17, c1) \
    { float h0 = tanh_fast(c0[0]); float h1 = tanh_fast(c1[0]); \
      asm("v_cvt_pk_bf16_f32 %0, %1, %2" : "=v"(SVNEW##0) : "v"(h0), "v"(h1)); \
      *(unsigned int*)&hbl[(P) ^ 1][lg * 4 + 0][n0 + 2 * l15] = SVNEW##0; } \
    { float h0 = tanh_fast(c0[1]); float h1 = tanh_fast(c1[1]); \
      asm("v_cvt_pk_bf16_f32 %0, %1, %2" : "=v"(SVNEW##1) : "v"(h0), "v"(h1)); \
      *(unsigned int*)&hbl[(P) ^ 1][lg * 4 + 1][n0 + 2 * l15] = SVNEW##1; } \
    { float h0 = tanh_fast(c0[2]); float h1 = tanh_fast(c1[2]); \
      asm("v_cvt_pk_bf16_f32 %0, %1, %2" : "=v"(SVNEW##2) : "v"(h0), "v"(h1)); \
      *(unsigned int*)&hbl[(P) ^ 1][lg * 4 + 2][n0 + 2 * l15] = SVNEW##2; } \
    { float h0 = tanh_fast(c0[3]); float h1 = tanh_fast(c1[3]); \
      asm("v_cvt_pk_bf16_f32 %0, %1, %2" : "=v"(SVNEW##3) : "v"(h0), "v"(h1)); \
      *(unsigned int*)&hbl[(P) ^ 1][lg * 4 + 3][n0 + 2 * l15] = SVNEW##3; } \
    __builtin_amdgcn_sched_barrier(0); \
    asm volatile("s_waitcnt lgkmcnt(0)" ::: "memory"); \
    __builtin_amdgcn_s_barrier(); \
    asm volatile("" ::: "memory"); \
    __builtin_amdgcn_sched_barrier(0); \
}

    for (int t = 0; t < TT; t += 2) {
        // step t (even): reads hbl[0], writes hbl[1]; loads x(t+1); stores sv(t-1)
        STEP(0, xvA, xvB, svB, svA, (t != 0), HH * 4, 0)
        // step t+1 (odd): reads hbl[1], writes hbl[0]; loads x(t+2); stores sv(t)
        STEP(1, xvB, xvA, svA, svB, 1, HH * 8, HH * 2)
        xq0 += 2 * HH; xq1 += 2 * HH; xq2 += 2 * HH; xq3 += 2 * HH;
        hq0 += 2 * HH; hq1 += 2 * HH; hq2 += 2 * HH; hq3 += 2 * HH;
    }

    // final stores: svB holds t = TT-1; hq now points at position TT-1
    *(unsigned int*)hq0 = svB0;
    *(unsigned int*)hq1 = svB1;
    *(unsigned int*)hq2 = svB2;
    *(unsigned int*)hq3 = svB3;
}

// ---------------------------------------------------------------------------
extern "C" void kernel_launch(void* const* d_in, const int* in_sizes, int n_in,
                              void* d_out, int out_size, void* d_ws, size_t ws_size,
                              hipStream_t stream)
{
    const float* x  = (const float*)d_in[0];   // [B,T,I]
    const float* Wi = (const float*)d_in[1];   // [H,I]
    const float* bi = (const float*)d_in[2];   // [H]
    const float* Wh = (const float*)d_in[3];   // [H,H]
    const float* bh = (const float*)d_in[4];   // [H]
    const float* Wo = (const float*)d_in[5];   // [O,H]
    const float* bo = (const float*)d_in[6];   // [O]
    float* out = (float*)d_out;                // [B,T,O] fp32

    const int M = BB * TT;                     // 131072 flattened rows

    // workspace: xproj fp32 [M,H] (134MB, permuted) | hs bf16 [M,H] (67MB, permuted)
    float* xproj = (float*)d_ws;
    unsigned short* hs = (unsigned short*)((char*)d_ws + (size_t)M * HH * sizeof(float));

    // Phase 1: xproj = x*Wi^T + (bi+bh), within-32 permuted columns
    gemm_f32_bt<<<dim3(M / BM, HH / BN), 256, 0, stream>>>(x, Wi, bi, bh, xproj, M, HH, II);

    // Phase 2: recurrence (4 CUs, 8 waves each, MFMA)
    rnn_recurrence_mfma<<<dim3(4), 512, 0, stream>>>(xproj, Wh, hs);

    // Phase 3: out = hs*Wo^T + bo (As staging un-permutes)
    gemm_bf16a_bt<<<dim3(M / BM, OO / BN), 256, 0, stream>>>(
        hs, Wo, bo, out, M, OO, HH);
}